// Round 1
// baseline (5653.505 us; speedup 1.0000x reference)
//
#include <hip/hip_runtime.h>
#include <math.h>

#define B 256
#define T 128
#define DD 300
#define H 512
#define FH 2048            // 4*H
#define BH (B*H)           // 131072

__device__ __forceinline__ float sigm(float x) { return 1.0f / (1.0f + expf(-x)); }

// ---------------------------------------------------------------------------
// Input projection: Xproj[ti*B+b][n] = sum_k X[b][t0+ti][k]*W[k][n] + bias[n]
// Tile 64x64, 256 threads, 4x4 per thread, Ktile=16 (K=300 with guards).
// blockIdx.z: 0 = premises, 1 = hypotheses.
// ---------------------------------------------------------------------------
__global__ __launch_bounds__(256)
void inproj_kernel(const float* __restrict__ Xp, const float* __restrict__ Xh,
                   const float* __restrict__ Wp, const float* __restrict__ bp,
                   const float* __restrict__ Wh, const float* __restrict__ bh,
                   float* __restrict__ Op, float* __restrict__ Oh, int t0)
{
    const int z = blockIdx.z;
    const float* X    = z ? Xh : Xp;
    const float* W    = z ? Wh : Wp;
    const float* bias = z ? bh : bp;
    float* O          = z ? Oh : Op;

    const int n0 = blockIdx.x * 64;
    const int m0 = blockIdx.y * 64;
    const int t  = threadIdx.x;
    const int rc = t >> 4, cc = t & 15;

    __shared__ float As[16][68];   // A^T: [k][row], padded for banks/alignment
    __shared__ float Bs[16][64];

    float acc[4][4] = {};
    float areg[4];
    float breg[4];

    // A load mapping: row = t/4 (0..63), kq = (t%4)*4
    const int ar = t >> 2;
    const int kq = (t & 3) * 4;
    // B load mapping: krow = t/16, n4 = (t%16)*4
    const int kb = t >> 4;
    const int nb = (t & 15) * 4;

    const int rg_a = m0 + ar;               // global row for A load
    const int bb   = rg_a & (B - 1);        // row = ti*B + b
    const int ti_a = rg_a >> 8;
    const float* arow = X + ((size_t)bb * T + (size_t)(t0 + ti_a)) * DD;

    const int KT = (DD + 15) / 16;          // 19

    // prologue: load tile 0
    {
        const int kk = kq;
        if (kk + 3 < DD) {
            float4 v = *(const float4*)(arow + kk);
            areg[0]=v.x; areg[1]=v.y; areg[2]=v.z; areg[3]=v.w;
        } else {
            #pragma unroll
            for (int j = 0; j < 4; ++j) areg[j] = (kk + j < DD) ? arow[kk + j] : 0.0f;
        }
        if (kb < DD) {
            float4 v = *(const float4*)(W + (size_t)kb * FH + n0 + nb);
            breg[0]=v.x; breg[1]=v.y; breg[2]=v.z; breg[3]=v.w;
        } else {
            breg[0]=breg[1]=breg[2]=breg[3]=0.0f;
        }
    }

    for (int kt = 0; kt < KT; ++kt) {
        __syncthreads();
        As[kq+0][ar] = areg[0];
        As[kq+1][ar] = areg[1];
        As[kq+2][ar] = areg[2];
        As[kq+3][ar] = areg[3];
        *(float4*)&Bs[kb][nb] = make_float4(breg[0], breg[1], breg[2], breg[3]);
        __syncthreads();

        if (kt + 1 < KT) {
            const int k0 = (kt + 1) * 16;
            const int kk = k0 + kq;
            if (kk + 3 < DD) {
                float4 v = *(const float4*)(arow + kk);
                areg[0]=v.x; areg[1]=v.y; areg[2]=v.z; areg[3]=v.w;
            } else {
                #pragma unroll
                for (int j = 0; j < 4; ++j) areg[j] = (kk + j < DD) ? arow[kk + j] : 0.0f;
            }
            if (k0 + kb < DD) {
                float4 v = *(const float4*)(W + (size_t)(k0 + kb) * FH + n0 + nb);
                breg[0]=v.x; breg[1]=v.y; breg[2]=v.z; breg[3]=v.w;
            } else {
                breg[0]=breg[1]=breg[2]=breg[3]=0.0f;
            }
        }

        #pragma unroll
        for (int k = 0; k < 16; ++k) {
            const float4 a = *(const float4*)&As[k][4*rc];
            const float4 b = *(const float4*)&Bs[k][4*cc];
            acc[0][0] += a.x*b.x; acc[0][1] += a.x*b.y; acc[0][2] += a.x*b.z; acc[0][3] += a.x*b.w;
            acc[1][0] += a.y*b.x; acc[1][1] += a.y*b.y; acc[1][2] += a.y*b.z; acc[1][3] += a.y*b.w;
            acc[2][0] += a.z*b.x; acc[2][1] += a.z*b.y; acc[2][2] += a.z*b.z; acc[2][3] += a.z*b.w;
            acc[3][0] += a.w*b.x; acc[3][1] += a.w*b.y; acc[3][2] += a.w*b.z; acc[3][3] += a.w*b.w;
        }
    }

    const float4 bv = *(const float4*)(bias + n0 + 4*cc);
    #pragma unroll
    for (int ri = 0; ri < 4; ++ri) {
        const int rg = m0 + 4*rc + ri;
        float4 res;
        res.x = acc[ri][0] + bv.x;
        res.y = acc[ri][1] + bv.y;
        res.z = acc[ri][2] + bv.z;
        res.w = acc[ri][3] + bv.w;
        *(float4*)&O[(size_t)rg * FH + n0 + 4*cc] = res;
    }
}

// ---------------------------------------------------------------------------
// Fused LSTM step: z = Xproj_t + h_in @ W_h ; gates ; update c, h_out.
// Block computes [32 batch rows] x [32 h-cols] x [4 gates]; 256 threads,
// 2x2x4 accumulators per thread. Grid (H/32=16, B/32=8, 2) = 256 blocks.
// ---------------------------------------------------------------------------
__global__ __launch_bounds__(256)
void lstm_step_kernel(const float* __restrict__ XPp, const float* __restrict__ XPh,
                      const float* __restrict__ Wp,  const float* __restrict__ Wh,
                      const float* __restrict__ Hp_in, float* __restrict__ Hp_out, float* __restrict__ Cp,
                      const float* __restrict__ Hh_in, float* __restrict__ Hh_out, float* __restrict__ Ch)
{
    const int z = blockIdx.z;
    const float* XP  = z ? XPh : XPp;
    const float* W   = z ? Wh  : Wp;    // full [D+H][4H]; h-part rows start at DD
    const float* Hin = z ? Hh_in : Hp_in;
    float* Hout      = z ? Hh_out : Hp_out;
    float* C         = z ? Ch : Cp;

    const int c0 = blockIdx.x * 32;   // h-dim col tile
    const int r0 = blockIdx.y * 32;   // batch row tile
    const int t  = threadIdx.x;
    const int rc = t >> 4, cc = t & 15;

    __shared__ float As[32][34];      // A^T [k][row]
    __shared__ float Bs[4][32][36];   // [gate][k][n]

    float acc[2][2][4];
    // init accumulators from Xproj (bias already folded in by inproj)
    #pragma unroll
    for (int ri = 0; ri < 2; ++ri) {
        const int r = r0 + 2*rc + ri;
        #pragma unroll
        for (int g = 0; g < 4; ++g) {
            const float2 v = *(const float2*)&XP[(size_t)r * FH + g*H + c0 + 2*cc];
            acc[ri][0][g] = v.x;
            acc[ri][1][g] = v.y;
        }
    }

    // staging regs
    float areg[4];
    float breg[4][4];
    const int lar = t >> 3;            // A row 0..31
    const int lak = (t & 7) * 4;       // A k offset
    const int lbk = t >> 3;            // B k row 0..31
    const int lbn = (t & 7) * 4;       // B n offset

    // prologue: tile 0
    {
        const float4 av = *(const float4*)&Hin[(size_t)(r0 + lar) * H + lak];
        areg[0]=av.x; areg[1]=av.y; areg[2]=av.z; areg[3]=av.w;
        #pragma unroll
        for (int g = 0; g < 4; ++g) {
            const float4 bv = *(const float4*)&W[(size_t)(DD + lbk) * FH + g*H + c0 + lbn];
            breg[g][0]=bv.x; breg[g][1]=bv.y; breg[g][2]=bv.z; breg[g][3]=bv.w;
        }
    }

    for (int kt = 0; kt < 16; ++kt) {
        __syncthreads();
        As[lak+0][lar] = areg[0];
        As[lak+1][lar] = areg[1];
        As[lak+2][lar] = areg[2];
        As[lak+3][lar] = areg[3];
        #pragma unroll
        for (int g = 0; g < 4; ++g)
            *(float4*)&Bs[g][lbk][lbn] = make_float4(breg[g][0], breg[g][1], breg[g][2], breg[g][3]);
        __syncthreads();

        if (kt + 1 < 16) {
            const int k0 = (kt + 1) * 32;
            const float4 av = *(const float4*)&Hin[(size_t)(r0 + lar) * H + k0 + lak];
            areg[0]=av.x; areg[1]=av.y; areg[2]=av.z; areg[3]=av.w;
            #pragma unroll
            for (int g = 0; g < 4; ++g) {
                const float4 bv = *(const float4*)&W[(size_t)(DD + k0 + lbk) * FH + g*H + c0 + lbn];
                breg[g][0]=bv.x; breg[g][1]=bv.y; breg[g][2]=bv.z; breg[g][3]=bv.w;
            }
        }

        #pragma unroll
        for (int k = 0; k < 32; ++k) {
            const float2 a = *(const float2*)&As[k][2*rc];
            #pragma unroll
            for (int g = 0; g < 4; ++g) {
                const float2 b = *(const float2*)&Bs[g][k][2*cc];
                acc[0][0][g] += a.x * b.x;
                acc[0][1][g] += a.x * b.y;
                acc[1][0][g] += a.y * b.x;
                acc[1][1][g] += a.y * b.y;
            }
        }
    }

    // gate epilogue: i, j, f, o ; c' = c*sig(f+1) + sig(i)*tanh(j); h' = tanh(c')*sig(o)
    #pragma unroll
    for (int ri = 0; ri < 2; ++ri) {
        const int r = r0 + 2*rc + ri;
        #pragma unroll
        for (int ci = 0; ci < 2; ++ci) {
            const int c = c0 + 2*cc + ci;
            const float i_ = acc[ri][ci][0];
            const float j_ = acc[ri][ci][1];
            const float f_ = acc[ri][ci][2];
            const float o_ = acc[ri][ci][3];
            const size_t idx = (size_t)r * H + c;
            const float cprev = C[idx];
            const float cn = cprev * sigm(f_ + 1.0f) + sigm(i_) * tanhf(j_);
            const float hn = tanhf(cn) * sigm(o_);
            C[idx] = cn;
            Hout[idx] = hn;
        }
    }
}

// ---------------------------------------------------------------------------
// Generic C = tanh(A @ W + bias), M=256 fixed tiles of 64x64, K multiple of 16.
// Writes to Cout[row*ldc + coloff + n].
// ---------------------------------------------------------------------------
__global__ __launch_bounds__(256)
void gemm_tanh_kernel(const float* __restrict__ A, const float* __restrict__ W,
                      const float* __restrict__ bias, float* __restrict__ Cout,
                      int K, int N, int ldc, int coloff)
{
    const int n0 = blockIdx.x * 64;
    const int m0 = blockIdx.y * 64;
    const int t  = threadIdx.x;
    const int rc = t >> 4, cc = t & 15;

    __shared__ float As[16][68];
    __shared__ float Bs[16][64];

    float acc[4][4] = {};
    float areg[4], breg[4];

    const int ar = t >> 2;
    const int kq = (t & 3) * 4;
    const int kb = t >> 4;
    const int nb = (t & 15) * 4;

    {
        const float4 av = *(const float4*)(A + (size_t)(m0 + ar) * K + kq);
        areg[0]=av.x; areg[1]=av.y; areg[2]=av.z; areg[3]=av.w;
        const float4 bv = *(const float4*)(W + (size_t)kb * N + n0 + nb);
        breg[0]=bv.x; breg[1]=bv.y; breg[2]=bv.z; breg[3]=bv.w;
    }

    const int KT = K / 16;
    for (int kt = 0; kt < KT; ++kt) {
        __syncthreads();
        As[kq+0][ar] = areg[0];
        As[kq+1][ar] = areg[1];
        As[kq+2][ar] = areg[2];
        As[kq+3][ar] = areg[3];
        *(float4*)&Bs[kb][nb] = make_float4(breg[0], breg[1], breg[2], breg[3]);
        __syncthreads();

        if (kt + 1 < KT) {
            const int k0 = (kt + 1) * 16;
            const float4 av = *(const float4*)(A + (size_t)(m0 + ar) * K + k0 + kq);
            areg[0]=av.x; areg[1]=av.y; areg[2]=av.z; areg[3]=av.w;
            const float4 bv = *(const float4*)(W + (size_t)(k0 + kb) * N + n0 + nb);
            breg[0]=bv.x; breg[1]=bv.y; breg[2]=bv.z; breg[3]=bv.w;
        }

        #pragma unroll
        for (int k = 0; k < 16; ++k) {
            const float4 a = *(const float4*)&As[k][4*rc];
            const float4 b = *(const float4*)&Bs[k][4*cc];
            acc[0][0] += a.x*b.x; acc[0][1] += a.x*b.y; acc[0][2] += a.x*b.z; acc[0][3] += a.x*b.w;
            acc[1][0] += a.y*b.x; acc[1][1] += a.y*b.y; acc[1][2] += a.y*b.z; acc[1][3] += a.y*b.w;
            acc[2][0] += a.z*b.x; acc[2][1] += a.z*b.y; acc[2][2] += a.z*b.z; acc[2][3] += a.z*b.w;
            acc[3][0] += a.w*b.x; acc[3][1] += a.w*b.y; acc[3][2] += a.w*b.z; acc[3][3] += a.w*b.w;
        }
    }

    const float4 bv = *(const float4*)(bias + n0 + 4*cc);
    #pragma unroll
    for (int ri = 0; ri < 4; ++ri) {
        const int rg = m0 + 4*rc + ri;
        float4 res;
        res.x = tanhf(acc[ri][0] + bv.x);
        res.y = tanhf(acc[ri][1] + bv.y);
        res.z = tanhf(acc[ri][2] + bv.z);
        res.w = tanhf(acc[ri][3] + bv.w);
        *(float4*)&Cout[(size_t)rg * ldc + coloff + n0 + 4*cc] = res;
    }
}

// ---------------------------------------------------------------------------
// Final projection: out[256][3] = t3 @ W_out + b_out. One wave per row.
// ---------------------------------------------------------------------------
__global__ __launch_bounds__(256)
void out_kernel(const float* __restrict__ A, const float* __restrict__ Wo,
                const float* __restrict__ bo, float* __restrict__ out)
{
    const int wave = threadIdx.x >> 6;
    const int lane = threadIdx.x & 63;
    const int r = blockIdx.x * 4 + wave;

    float a0 = 0.f, a1 = 0.f, a2 = 0.f;
    for (int k = lane; k < 1024; k += 64) {
        const float a = A[(size_t)r * 1024 + k];
        a0 += a * Wo[k*3 + 0];
        a1 += a * Wo[k*3 + 1];
        a2 += a * Wo[k*3 + 2];
    }
    #pragma unroll
    for (int off = 32; off > 0; off >>= 1) {
        a0 += __shfl_down(a0, off);
        a1 += __shfl_down(a1, off);
        a2 += __shfl_down(a2, off);
    }
    if (lane == 0) {
        out[r*3 + 0] = a0 + bo[0];
        out[r*3 + 1] = a1 + bo[1];
        out[r*3 + 2] = a2 + bo[2];
    }
}

// ---------------------------------------------------------------------------
extern "C" void kernel_launch(void* const* d_in, const int* in_sizes, int n_in,
                              void* d_out, int out_size, void* d_ws, size_t ws_size,
                              hipStream_t stream)
{
    const float* premises   = (const float*)d_in[0];
    const float* hypotheses = (const float*)d_in[1];
    const float* W_lstm_p   = (const float*)d_in[2];
    const float* b_lstm_p   = (const float*)d_in[3];
    const float* W_lstm_h   = (const float*)d_in[4];
    const float* b_lstm_h   = (const float*)d_in[5];
    const float* W_red_p    = (const float*)d_in[6];
    const float* b_red_p    = (const float*)d_in[7];
    const float* W_red_h    = (const float*)d_in[8];
    const float* b_red_h    = (const float*)d_in[9];
    const float* W1 = (const float*)d_in[10];  const float* b1 = (const float*)d_in[11];
    const float* W2 = (const float*)d_in[12];  const float* b2 = (const float*)d_in[13];
    const float* W3 = (const float*)d_in[14];  const float* b3 = (const float*)d_in[15];
    const float* W_out = (const float*)d_in[16]; const float* b_out = (const float*)d_in[17];
    float* out = (float*)d_out;
    float* ws  = (float*)d_ws;

    // workspace layout (floats)
    float* c_p    = ws + 0 * (size_t)BH;
    float* c_h    = ws + 1 * (size_t)BH;
    float* h_p[2] = { ws + 2 * (size_t)BH, ws + 3 * (size_t)BH };
    float* h_h[2] = { ws + 4 * (size_t)BH, ws + 5 * (size_t)BH };
    float* xbuf   = ws + 6 * (size_t)BH;    // [256][1024]
    float* t1b    = ws + 8 * (size_t)BH;
    float* t2b    = ws + 10 * (size_t)BH;
    float* t3b    = ws + 12 * (size_t)BH;
    float* xp_chunk = ws + 14 * (size_t)BH;

    // chunk length over T: largest CT whose Xproj buffers fit ws
    int CT = 1;
    for (int c = 128; c >= 1; c >>= 1) {
        size_t need = (size_t)(14 + 8 * (size_t)c) * BH * sizeof(float);
        if (need <= ws_size) { CT = c; break; }
    }
    float* xh_chunk = xp_chunk + (size_t)CT * B * FH;

    // zero c and h ping-pong buffers (ws is poisoned before every call)
    hipMemsetAsync(ws, 0, 6 * (size_t)BH * sizeof(float), stream);

    const int nchunks = T / CT;
    for (int ch = 0; ch < nchunks; ++ch) {
        const int t0 = ch * CT;
        dim3 g1(FH / 64, (CT * B) / 64, 2);
        inproj_kernel<<<g1, 256, 0, stream>>>(premises, hypotheses,
                                              W_lstm_p, b_lstm_p, W_lstm_h, b_lstm_h,
                                              xp_chunk, xh_chunk, t0);
        for (int ti = 0; ti < CT; ++ti) {
            const int tt = t0 + ti;
            const float* XPp = xp_chunk + (size_t)ti * B * FH;
            const float* XPh = xh_chunk + (size_t)ti * B * FH;
            dim3 g2(H / 32, B / 32, 2);
            lstm_step_kernel<<<g2, 256, 0, stream>>>(XPp, XPh, W_lstm_p, W_lstm_h,
                h_p[tt & 1], h_p[(tt + 1) & 1], c_p,
                h_h[tt & 1], h_h[(tt + 1) & 1], c_h);
        }
    }
    // T even -> final hidden states live in buffer 0
    dim3 gr(H / 64, B / 64);
    gemm_tanh_kernel<<<gr, 256, 0, stream>>>(h_p[0], W_red_p, b_red_p, xbuf, H, H, 1024, 0);
    gemm_tanh_kernel<<<gr, 256, 0, stream>>>(h_h[0], W_red_h, b_red_h, xbuf, H, H, 1024, 512);
    dim3 gm(1024 / 64, B / 64);
    gemm_tanh_kernel<<<gm, 256, 0, stream>>>(xbuf, W1, b1, t1b, 1024, 1024, 1024, 0);
    gemm_tanh_kernel<<<gm, 256, 0, stream>>>(t1b, W2, b2, t2b, 1024, 1024, 1024, 0);
    gemm_tanh_kernel<<<gm, 256, 0, stream>>>(t2b, W3, b3, t3b, 1024, 1024, 1024, 0);
    out_kernel<<<B / 4, 256, 0, stream>>>(t3b, W_out, b_out, out);
}